// Round 12
// baseline (121.919 us; speedup 1.0000x reference)
//
#include <hip/hip_runtime.h>

// CostConcatenation: out[b,d,h,w, 0:16] = left[b,h,w,:]        (if valid else 0)
//                    out[b,d,h,w,16:32] = right[b,h,w-disp,:]  (if valid else 0)
// disp = d - 112 ; idx = w + (112 - d) ; valid = 0<=idx<W
// Output (B, D, H, W, 2C) fp32 = 604 MB -> write-BW bound.
// History: R1 plain/scattered 129us. R3 nt/scattered 118us. R4 d-tile null.
// R5 sc0/sc1 nan. R6 XCD -6%. R7 nt/persistent-linear 115.9us (5.2 TB/s;
// fill comparator 6.76 TB/s uses PLAIN stores). R8 branchless -3%. R9 deep
// pipeline -13%. R10 memcpy-shape -11%. R11 LDS zero-load loop 120us ->
// reads exonerated.
// R12: the untested matrix cell - PLAIN cached stores + persistent linear
// sweep. Tests whether nt bypasses L2 write-combining (64B sectors vs 128B
// bursts) and was only a local fix for the scattered-order L2 thrash.

constexpr int B_ = 2;
constexpr int H_ = 96;
constexpr int W_ = 192;
constexpr int D_ = 128;

typedef float v4f __attribute__((ext_vector_type(4)));

constexpr unsigned TOTAL4   = 37748736u;      // B*D*H*W*8 float4 (604 MB)
constexpr unsigned NBLK     = 2048u;          // 8 blocks/CU
constexpr unsigned NTHREADS = NBLK * 256u;    // 524288
constexpr int      ITERS    = TOTAL4 / NTHREADS;  // 72

__global__ __launch_bounds__(256) void cost_concat_kernel(
    const v4f* __restrict__ left,
    const v4f* __restrict__ right,
    v4f* __restrict__ out)
{
    unsigned j = blockIdx.x * 256u + threadIdx.x;

    #pragma unroll 4
    for (int it = 0; it < ITERS; ++it, j += NTHREADS) {
        // decode flat float4 index -> (rowid, w, c4); rowid = (b*128+d)*96+h
        const unsigned rowid = j / 1536u;            // magic mul
        const unsigned rr    = j - rowid * 1536u;
        const unsigned w     = rr >> 3;
        const unsigned c4    = rr & 7u;
        const unsigned b     = rowid / 12288u;       // 128*96
        const unsigned t     = rowid - b * 12288u;
        const unsigned d     = t / 96u;              // magic mul
        const unsigned h     = t - d * 96u;

        const int idx = (int)w + 112 - (int)d;       // right-image column
        const unsigned rowBase = (b * H_ + h) * (W_ * 4);  // input row, float4

        v4f v = (v4f)(0.f);
        if ((unsigned)idx < (unsigned)W_) {
            const v4f* src = (c4 < 4u)
                ? (left  + rowBase + w * 4u + c4)
                : (right + rowBase + (unsigned)idx * 4u + (c4 - 4u));
            v = *src;
        }
        out[j] = v;                                   // PLAIN cached store
    }
}

extern "C" void kernel_launch(void* const* d_in, const int* in_sizes, int n_in,
                              void* d_out, int out_size, void* d_ws, size_t ws_size,
                              hipStream_t stream)
{
    const v4f* left  = (const v4f*)d_in[0];
    const v4f* right = (const v4f*)d_in[1];
    v4f* out = (v4f*)d_out;

    cost_concat_kernel<<<dim3(NBLK), 256, 0, stream>>>(left, right, out);
}

// Round 13
// 117.788 us; speedup vs baseline: 1.0351x; 1.0351x over previous
//
#include <hip/hip_runtime.h>

// CostConcatenation: out[b,d,h,w, 0:16] = left[b,h,w,:]        (if valid else 0)
//                    out[b,d,h,w,16:32] = right[b,h,w-disp,:]  (if valid else 0)
// disp = d - 112 ; idx = w + (112 - d) ; valid = 0<=idx<W
// Output (B, D, H, W, 2C) fp32 = 604 MB -> write-BW bound.
//
// FINAL (R7 structure, best = 115.9 us = 5.2 TB/s effective write BW):
//   - 2048 persistent blocks (8/CU), linear grid-stride sweep of flat output
//   - nontemporal stores (+10% vs plain scattered, +5% vs plain linear)
//   - guarded cache-served loads (inputs 4.7 MB, L2/L3-resident)
// Exhausted matrix: sc0/sc1 bypass -> harness-incoherent (nan). Read-locality
// (d-tile, XCD stripe, LDS zero-load staging) null-to-negative: reads are
// cache-absorbed and never throttle the store stream. Branchless clamped
// loads -3%. 8-deep load batching -13%. 2-blocks/CU contiguous segments -11%.
// Residual gap to the 6.76 TB/s fill comparator == launch/ramp amortization
// (fill writes 2.4 GB over 4x the duration, zero reads) -> practical ceiling.

constexpr int B_ = 2;
constexpr int H_ = 96;
constexpr int W_ = 192;
constexpr int D_ = 128;

typedef float v4f __attribute__((ext_vector_type(4)));

constexpr unsigned TOTAL4   = 37748736u;      // B*D*H*W*8 float4 (604 MB)
constexpr unsigned NBLK     = 2048u;          // 8 blocks/CU
constexpr unsigned NTHREADS = NBLK * 256u;    // 524288
constexpr int      ITERS    = TOTAL4 / NTHREADS;  // 72

__global__ __launch_bounds__(256) void cost_concat_kernel(
    const v4f* __restrict__ left,
    const v4f* __restrict__ right,
    v4f* __restrict__ out)
{
    unsigned j = blockIdx.x * 256u + threadIdx.x;

    #pragma unroll 4
    for (int it = 0; it < ITERS; ++it, j += NTHREADS) {
        // decode flat float4 index -> (rowid, w, c4); rowid = (b*128+d)*96+h
        const unsigned rowid = j / 1536u;            // magic mul
        const unsigned rr    = j - rowid * 1536u;
        const unsigned w     = rr >> 3;
        const unsigned c4    = rr & 7u;
        const unsigned b     = rowid / 12288u;       // 128*96
        const unsigned t     = rowid - b * 12288u;
        const unsigned d     = t / 96u;              // magic mul
        const unsigned h     = t - d * 96u;

        const int idx = (int)w + 112 - (int)d;       // right-image column
        const unsigned rowBase = (b * H_ + h) * (W_ * 4);  // input row, float4

        v4f v = (v4f)(0.f);
        if ((unsigned)idx < (unsigned)W_) {
            const v4f* src = (c4 < 4u)
                ? (left  + rowBase + w * 4u + c4)
                : (right + rowBase + (unsigned)idx * 4u + (c4 - 4u));
            v = *src;
        }
        __builtin_nontemporal_store(v, out + j);
    }
}

extern "C" void kernel_launch(void* const* d_in, const int* in_sizes, int n_in,
                              void* d_out, int out_size, void* d_ws, size_t ws_size,
                              hipStream_t stream)
{
    const v4f* left  = (const v4f*)d_in[0];
    const v4f* right = (const v4f*)d_in[1];
    v4f* out = (v4f*)d_out;

    cost_concat_kernel<<<dim3(NBLK), 256, 0, stream>>>(left, right, out);
}